// Round 4
// baseline (2249.647 us; speedup 1.0000x reference)
//
#include <hip/hip_runtime.h>
#include <hip/hip_bf16.h>

typedef __attribute__((ext_vector_type(8))) short short8;
typedef __attribute__((ext_vector_type(4))) float f32x4;
typedef __hip_bfloat16 bf16;

__device__ __forceinline__ short f2bs(float f) {
    bf16 b = __float2bfloat16(f);
    return *reinterpret_cast<const short*>(&b);
}
__device__ __forceinline__ float bs2f(short s) {
    bf16 b = *reinterpret_cast<const bf16*>(&s);
    return __bfloat162float(b);
}
__device__ __forceinline__ float ldf(const void* p, int i, int flag) {
    return flag ? bs2f(((const short*)p)[i]) : ((const float*)p)[i];
}
__device__ __forceinline__ short ldbits(const void* p, int i, int flag) {
    return flag ? ((const short*)p)[i] : f2bs(((const float*)p)[i]);
}
__device__ __forceinline__ void stf(void* p, int i, float v, int flag) {
    if (flag) ((bf16*)p)[i] = __float2bfloat16(v);
    else ((float*)p)[i] = v;
}
__device__ __forceinline__ float nz(float v) { return (v == v) ? v : 0.f; }
__device__ __forceinline__ float siluf(float v) {
    float t = __expf(fminf(fmaxf(-v, -80.f), 80.f));
    return v / (1.f + t);
}
__device__ __forceinline__ float sigmf(float v) {
    float t = __expf(fminf(fmaxf(-v, -80.f), 80.f));
    return 1.f / (1.f + t);
}

// ---------------------------------------------------------------------------
__global__ void detect_kernel(const unsigned int* __restrict__ hw, int* __restrict__ flag) {
    unsigned int w = hw[threadIdx.x];
    unsigned int e = (w >> 7) & 0xFF;
    bool ok = (e >= 113 && e <= 135);
    unsigned long long m = __ballot(ok);
    if (threadIdx.x == 0) *flag = (__popcll(m) >= 32) ? 1 : 0;
}

// ---------------------------------------------------------------------------
__global__ void prep_kernel(
    const void* eW1, const void* eW2, const void* cW1, const void* iW1,
    const void* eb1, const void* eb2, const void* cb1, const void* cw2,
    const void* ib1, const void* iw2, const void* ib2, const void* nb1,
    const void* nb2, const void* vb1, const void* vW2,
    const void* nW1, const void* nW2, const void* vW1,
    short* __restrict__ W1t, short* __restrict__ W2t,
    short* __restrict__ cW1t, short* __restrict__ iW1t,
    float* __restrict__ biasblk, float* __restrict__ nW1f,
    float* __restrict__ nW2f, float* __restrict__ vW1f,
    const int* __restrict__ flagp) {
    const int flag = *flagp;
    int i = blockIdx.x * 256 + threadIdx.x;
    if (i < 36864) { int n = i / 288, k = i % 288; W1t[i] = (k < 258) ? ldbits(eW1, k * 128 + n, flag) : (short)0; return; }
    i -= 36864;
    if (i < 16384) { int n = i / 128, k = i % 128; W2t[i] = ldbits(eW2, k * 128 + n, flag); return; }
    i -= 16384;
    if (i < 16384) { int n = i / 128, k = i % 128; cW1t[i] = ldbits(cW1, k * 128 + n, flag); return; }
    i -= 16384;
    if (i < 8192) { int n = i / 128, k = i % 128; iW1t[i] = ldbits(iW1, k * 64 + n, flag); return; }
    i -= 8192;
    if (i < 1156) {
        float v;
        if (i < 128) v = ldf(eb1, i, flag);
        else if (i < 256) v = ldf(eb2, i - 128, flag);
        else if (i < 384) v = ldf(cb1, i - 256, flag);
        else if (i < 512) v = ldf(cw2, i - 384, flag);
        else if (i < 576) v = ldf(ib1, i - 512, flag);
        else if (i < 640) v = ldf(iw2, i - 576, flag);
        else if (i < 644) v = (i == 640) ? ldf(ib2, 0, flag) : 0.f;
        else if (i < 772) v = ldf(nb1, i - 644, flag);
        else if (i < 900) v = ldf(nb2, i - 772, flag);
        else if (i < 1028) v = ldf(vb1, i - 900, flag);
        else v = ldf(vW2, i - 1028, flag);
        biasblk[i] = v;
        return;
    }
    i -= 1156;
    if (i < 32768) { nW1f[i] = ldf(nW1, i, flag); return; }
    i -= 32768;
    if (i < 16384) { nW2f[i] = ldf(nW2, i, flag); return; }
    i -= 16384;
    if (i < 16384) { vW1f[i] = ldf(vW1, i, flag); }
}

// ---------------------------------------------------------------------------
__global__ void convh_kernel(const void* __restrict__ h, short* __restrict__ hb,
                             const int* __restrict__ flagp, int n) {
    const int flag = *flagp;
    int i = blockIdx.x * 256 + threadIdx.x;
    if (i < n) hb[i] = ldbits(h, i, flag);
}

// ---------------------------------------------------------------------------
// CSR build: count -> scan (exclusive prefix) -> fill
// ---------------------------------------------------------------------------
__global__ void count_kernel(const int* __restrict__ erow, int* __restrict__ cnt, int E) {
    int i = blockIdx.x * 256 + threadIdx.x;
    if (i < E) atomicAdd(&cnt[erow[i]], 1);
}

__global__ __launch_bounds__(1024) void scan_kernel(const int* __restrict__ cnt,
                                                    int* __restrict__ off, int N) {
    __shared__ int sm[1024];
    __shared__ int carrysh;
    const int t = threadIdx.x;
    if (t == 0) carrysh = 0;
    __syncthreads();
    for (int base = 0; base < N; base += 1024) {
        int idx = base + t;
        int c = (idx < N) ? cnt[idx] : 0;
        sm[t] = c;
        __syncthreads();
        for (int d = 1; d < 1024; d <<= 1) {
            int v = (t >= d) ? sm[t - d] : 0;
            __syncthreads();
            sm[t] += v;
            __syncthreads();
        }
        int carry = carrysh;
        if (idx < N) off[idx] = carry + sm[t] - c;
        __syncthreads();
        if (t == 1023) carrysh = carry + sm[1023];
        __syncthreads();
    }
}

__global__ void fill_kernel(const int* __restrict__ erow, const int* __restrict__ off,
                            int* __restrict__ cur, int* __restrict__ elist, int E) {
    int i = blockIdx.x * 256 + threadIdx.x;
    if (i < E) {
        int r = erow[i];
        int p = off[r] + atomicAdd(&cur[r], 1);
        elist[p] = i;
    }
}

// ---------------------------------------------------------------------------
// edge kernel: fused edge MLP + inf + coord.
// ATOMIC=true: scatter via atomics (fallback). ATOMIC=false: plain stores to
// mbuf (e*m_ij, fp32 [E][128]) and xbuf (e*phi*x_diff, fp32 [E][4]).
// ---------------------------------------------------------------------------
template <bool ATOMIC>
__global__ __launch_bounds__(256) void edge_kernel(
    const short* __restrict__ hb, const void* __restrict__ x,
    const void* __restrict__ eattr,
    const int* __restrict__ erow, const int* __restrict__ ecol,
    const short* __restrict__ W1t, const short* __restrict__ W2t,
    const short* __restrict__ cW1t, const short* __restrict__ iW1t,
    const float* __restrict__ b1f, const float* __restrict__ b2f,
    const float* __restrict__ cb1f, const float* __restrict__ cw2f,
    const float* __restrict__ ib1f, const float* __restrict__ iw2f,
    const float* __restrict__ ib2f,
    float* __restrict__ mbuf, float* __restrict__ xbuf,
    float* __restrict__ m_i, float* __restrict__ agg_x,
    int E, const int* __restrict__ flagp) {
    const int flag = *flagp;
    __shared__ __align__(16) short tiles[4][16 * 136];
    const int tid = threadIdx.x;
    const int wv = tid >> 6;
    const int lane = tid & 63;
    const int n15 = lane & 15;
    const int quad = lane >> 4;
    const int wb = blockIdx.x * 64 + wv * 16;

    const int e = wb + n15;
    const int eL = (e < E) ? e : (E - 1);
    const int row_e = erow[eL];
    const int col_e = ecol[eL];

    float dist = 0.f;
#pragma unroll
    for (int d = 0; d < 3; ++d) {
        float xd = ldf(x, row_e * 3 + d, flag) - ldf(x, col_e * 3 + d, flag);
        dist += xd * xd;
    }
    dist = nz(dist);
    const float attr = nz(ldf(eattr, eL, flag));

    // ---- GEMM1: ef[16 x 288] @ W1 -> hidden1 [16 x 128]
    f32x4 acc1[8];
#pragma unroll
    for (int nt = 0; nt < 8; ++nt) acc1[nt] = (f32x4){0.f, 0.f, 0.f, 0.f};
#pragma unroll
    for (int kc = 0; kc < 9; ++kc) {
        short8 a;
        if (kc < 4) {
            a = *(const short8*)(hb + row_e * 128 + kc * 32 + quad * 8);
        } else if (kc < 8) {
            a = *(const short8*)(hb + col_e * 128 + (kc - 4) * 32 + quad * 8);
        } else {
#pragma unroll
            for (int t = 0; t < 8; ++t) a[t] = 0;
            if (quad == 0) { a[0] = f2bs(dist); a[1] = f2bs(attr); }
        }
#pragma unroll
        for (int nt = 0; nt < 8; ++nt) {
            short8 b = *(const short8*)(W1t + (nt * 16 + n15) * 288 + kc * 32 + quad * 8);
            acc1[nt] = __builtin_amdgcn_mfma_f32_16x16x32_bf16(a, b, acc1[nt], 0, 0, 0);
        }
    }

    short* tile = tiles[wv];
#pragma unroll
    for (int nt = 0; nt < 8; ++nt) {
        float bv = b1f[nt * 16 + n15];
#pragma unroll
        for (int r = 0; r < 4; ++r) {
            float v = nz(acc1[nt][r] + bv);
            tile[(quad * 4 + r) * 136 + nt * 16 + n15] = f2bs(siluf(v));
        }
    }
    __syncthreads();

    // ---- GEMM2: hidden1 @ W2 -> m_ij
    f32x4 acc2[8];
#pragma unroll
    for (int nt = 0; nt < 8; ++nt) acc2[nt] = (f32x4){0.f, 0.f, 0.f, 0.f};
#pragma unroll
    for (int kc = 0; kc < 4; ++kc) {
        short8 a = *(const short8*)(tile + n15 * 136 + kc * 32 + quad * 8);
#pragma unroll
        for (int nt = 0; nt < 8; ++nt) {
            short8 b = *(const short8*)(W2t + (nt * 16 + n15) * 128 + kc * 32 + quad * 8);
            acc2[nt] = __builtin_amdgcn_mfma_f32_16x16x32_bf16(a, b, acc2[nt], 0, 0, 0);
        }
    }
    float mv[8][4];
#pragma unroll
    for (int nt = 0; nt < 8; ++nt) {
        float bv = b2f[nt * 16 + n15];
#pragma unroll
        for (int r = 0; r < 4; ++r) mv[nt][r] = siluf(nz(acc2[nt][r] + bv));
    }
    __syncthreads();
#pragma unroll
    for (int nt = 0; nt < 8; ++nt)
#pragma unroll
        for (int r = 0; r < 4; ++r)
            tile[(quad * 4 + r) * 136 + nt * 16 + n15] = f2bs(mv[nt][r]);
    __syncthreads();

    // ---- GEMM3 (coord hidden) + GEMM4 (inf hidden)
    f32x4 acc3[8];
    f32x4 acc4[4];
#pragma unroll
    for (int nt = 0; nt < 8; ++nt) acc3[nt] = (f32x4){0.f, 0.f, 0.f, 0.f};
#pragma unroll
    for (int nt = 0; nt < 4; ++nt) acc4[nt] = (f32x4){0.f, 0.f, 0.f, 0.f};
#pragma unroll
    for (int kc = 0; kc < 4; ++kc) {
        short8 a = *(const short8*)(tile + n15 * 136 + kc * 32 + quad * 8);
#pragma unroll
        for (int nt = 0; nt < 8; ++nt) {
            short8 b = *(const short8*)(cW1t + (nt * 16 + n15) * 128 + kc * 32 + quad * 8);
            acc3[nt] = __builtin_amdgcn_mfma_f32_16x16x32_bf16(a, b, acc3[nt], 0, 0, 0);
        }
#pragma unroll
        for (int nt = 0; nt < 4; ++nt) {
            short8 b = *(const short8*)(iW1t + (nt * 16 + n15) * 128 + kc * 32 + quad * 8);
            acc4[nt] = __builtin_amdgcn_mfma_f32_16x16x32_bf16(a, b, acc4[nt], 0, 0, 0);
        }
    }

    // ---- epilogues
    float php[4] = {0.f, 0.f, 0.f, 0.f};
    float inp[4] = {0.f, 0.f, 0.f, 0.f};
#pragma unroll
    for (int nt = 0; nt < 8; ++nt) {
        float cb = cb1f[nt * 16 + n15];
        float cw = cw2f[nt * 16 + n15];
#pragma unroll
        for (int r = 0; r < 4; ++r) php[r] += siluf(nz(acc3[nt][r] + cb)) * cw;
    }
#pragma unroll
    for (int nt = 0; nt < 4; ++nt) {
        float ib = ib1f[nt * 16 + n15];
        float iw = iw2f[nt * 16 + n15];
#pragma unroll
        for (int r = 0; r < 4; ++r) inp[r] += siluf(nz(acc4[nt][r] + ib)) * iw;
    }
#pragma unroll
    for (int mk = 1; mk < 16; mk <<= 1) {
#pragma unroll
        for (int r = 0; r < 4; ++r) {
            php[r] += __shfl_xor(php[r], mk);
            inp[r] += __shfl_xor(inp[r], mk);
        }
    }
    const float ib2s = ib2f[0];
    float eij[4];
#pragma unroll
    for (int r = 0; r < 4; ++r) eij[r] = sigmf(nz(inp[r] + ib2s));

    int err[4], ecc[4];
    bool msk[4];
#pragma unroll
    for (int r = 0; r < 4; ++r) {
        err[r] = __shfl(row_e, quad * 4 + r);
        ecc[r] = __shfl(col_e, quad * 4 + r);
        msk[r] = (wb + quad * 4 + r) < E;
    }

    if (ATOMIC) {
#pragma unroll
        for (int nt = 0; nt < 8; ++nt) {
#pragma unroll
            for (int r = 0; r < 4; ++r) {
                if (msk[r]) atomicAdd(&m_i[err[r] * 128 + nt * 16 + n15], nz(eij[r] * mv[nt][r]));
            }
        }
        if (n15 == 0) {
#pragma unroll
            for (int r = 0; r < 4; ++r) {
                if (!msk[r]) continue;
                float s = eij[r] * php[r];
#pragma unroll
                for (int d = 0; d < 3; ++d) {
                    float xd = ldf(x, err[r] * 3 + d, flag) - ldf(x, ecc[r] * 3 + d, flag);
                    atomicAdd(&agg_x[err[r] * 3 + d], nz(s * xd));
                }
            }
        }
    } else {
        // plain coalesced-ish stores: mbuf[(wb+quad*4+r)*128 + nt*16+n15]
#pragma unroll
        for (int nt = 0; nt < 8; ++nt) {
#pragma unroll
            for (int r = 0; r < 4; ++r) {
                if (msk[r])
                    mbuf[(size_t)(wb + quad * 4 + r) * 128 + nt * 16 + n15] =
                        nz(eij[r] * mv[nt][r]);
            }
        }
        if (n15 < 3) {
#pragma unroll
            for (int r = 0; r < 4; ++r) {
                if (!msk[r]) continue;
                float s = __shfl(eij[r] * php[r], quad * 16);  // broadcast within quad
                int d = n15;
                float xd = ldf(x, err[r] * 3 + d, flag) - ldf(x, ecc[r] * 3 + d, flag);
                xbuf[(size_t)(wb + quad * 4 + r) * 4 + d] = nz(s * xd);
            }
        }
    }
}

// ---------------------------------------------------------------------------
// node kernel (fused): gather m_i (+agg_x), vel MLP, node MLP, x_out, v_out
// ---------------------------------------------------------------------------
template <bool GATHER>
__global__ __launch_bounds__(128) void node_kernel(
    const short* __restrict__ hb, const void* __restrict__ x,
    const void* __restrict__ v_init,
    const float* __restrict__ mbuf, const float* __restrict__ xbuf,
    const int* __restrict__ off, const int* __restrict__ cnt,
    const int* __restrict__ elist,
    const float* __restrict__ m_i, const float* __restrict__ agg_x,
    const float* __restrict__ nW1f, const float* __restrict__ nb1f,
    const float* __restrict__ nW2f, const float* __restrict__ nb2f,
    const float* __restrict__ vW1f, const float* __restrict__ vb1f,
    const float* __restrict__ vW2f,
    void* __restrict__ out, int xbase, int vbase, float inv_nm1,
    const int* __restrict__ flagp) {
    const int flag = *flagp;
    __shared__ float nin[256];
    __shared__ float red[128];
    __shared__ float hid[128];
    const int n = blockIdx.x, j = threadIdx.x;
    nin[j] = bs2f(hb[n * 128 + j]);

    float msum;
    const int s0 = GATHER ? off[n] : 0;
    const int c = cnt[n];
    if (GATHER) {
        msum = 0.f;
        for (int i = 0; i < c; ++i) {
            int eid = elist[s0 + i];
            msum += mbuf[(size_t)eid * 128 + j];
        }
    } else {
        msum = m_i[n * 128 + j];
    }
    nin[128 + j] = nz(msum);
    __syncthreads();

    // vel MLP
    float vacc = vb1f[j];
#pragma unroll 8
    for (int k = 0; k < 128; ++k) vacc += nin[k] * vW1f[k * 128 + j];
    red[j] = siluf(nz(vacc)) * vW2f[j];
    __syncthreads();
    for (int s = 64; s > 0; s >>= 1) {
        if (j < s) red[j] += red[j + s];
        __syncthreads();
    }
    const float vscale = red[0];
    __syncthreads();

    // node MLP
    float acc = nb1f[j];
#pragma unroll 8
    for (int k = 0; k < 256; ++k) acc += nin[k] * nW1f[k * 128 + j];
    hid[j] = siluf(nz(acc));
    __syncthreads();
    float o = nb2f[j];
#pragma unroll 8
    for (int k = 0; k < 128; ++k) o += hid[k] * nW2f[k * 128 + j];
    stf(out, n * 128 + j, nz(o), flag);

    if (j < 3) {
        float vj = nz(ldf(v_init, n * 3 + j, flag) * vscale);
        stf(out, vbase + n * 3 + j, vj, flag);
        float xv = ldf(x, n * 3 + j, flag);
        float ax;
        if (GATHER) {
            ax = 0.f;
            for (int i = 0; i < c; ++i) {
                int eid = elist[s0 + i];
                ax += xbuf[(size_t)eid * 4 + j];
            }
        } else {
            ax = agg_x[n * 3 + j];
        }
        float xo = (c > 0) ? xv + vj + nz(ax) * inv_nm1 : xv;
        stf(out, xbase + n * 3 + j, nz(xo), flag);
    }
}

// ---------------------------------------------------------------------------
extern "C" void kernel_launch(void* const* d_in, const int* in_sizes, int n_in,
                              void* d_out, int out_size, void* d_ws, size_t ws_size,
                              hipStream_t stream) {
    const void* h = d_in[0];
    const void* x = d_in[1];
    const void* eattr = d_in[2];
    const void* v_init = d_in[3];
    const int* eidx = (const int*)d_in[4];

    const int N = in_sizes[0] / 128;
    const int E = in_sizes[4] / 2;
    const int* erow = eidx;
    const int* ecol = eidx + E;

    char* ws = (char*)d_ws;
    int* flag = (int*)ws;
    short* W1t = (short*)(ws + 256);
    short* W2t = (short*)(ws + 73984);
    short* cW1t = (short*)(ws + 106752);
    short* iW1t = (short*)(ws + 139520);
    float* biasblk = (float*)(ws + 155904);
    float* nW1f = (float*)(ws + 160768);
    float* nW2f = (float*)(ws + 291840);
    float* vW1f = (float*)(ws + 357376);
    short* hb = (short*)(ws + 422912);
    size_t A = 422912 + (size_t)N * 256;

    // common: cnt at A
    int* cnt = (int*)(ws + A);
    // big path layout
    size_t oCur = A + (size_t)N * 4;
    int* cur = (int*)(ws + oCur);
    size_t oOff = oCur + (size_t)N * 4;
    int* offp = (int*)(ws + oOff);
    size_t oEl = oOff + (size_t)(N + 16) * 4;
    int* elist = (int*)(ws + oEl);
    size_t oXb = oEl + (size_t)E * 4;
    float* xbuf = (float*)(ws + oXb);
    size_t oMb = oXb + (size_t)E * 16;
    float* mbuf = (float*)(ws + oMb);
    size_t need = oMb + (size_t)E * 512;
    // fallback layout (overlaps big-path region beyond cnt)
    float* agg_x = (float*)(ws + A + (size_t)N * 4);
    float* m_i = (float*)(ws + A + (size_t)N * 16);

    const bool big = (ws_size >= need);

    float* b1f = biasblk + 0;
    float* b2f = biasblk + 128;
    float* cb1f = biasblk + 256;
    float* cw2f = biasblk + 384;
    float* ib1f = biasblk + 512;
    float* iw2f = biasblk + 576;
    float* ib2f = biasblk + 640;
    float* nb1f = biasblk + 644;
    float* nb2f = biasblk + 772;
    float* vb1f = biasblk + 900;
    float* vW2f = biasblk + 1028;

    detect_kernel<<<1, 64, 0, stream>>>((const unsigned int*)h, flag);

    const int prep_elems = 36864 + 16384 + 16384 + 8192 + 1156 + 32768 + 16384 + 16384;
    prep_kernel<<<(prep_elems + 255) / 256, 256, 0, stream>>>(
        d_in[5], d_in[7], d_in[9], d_in[12],
        d_in[6], d_in[8], d_in[10], d_in[11], d_in[13], d_in[14], d_in[15],
        d_in[17], d_in[19], d_in[21], d_in[22],
        d_in[16], d_in[18], d_in[20],
        W1t, W2t, cW1t, iW1t, biasblk, nW1f, nW2f, vW1f, flag);

    convh_kernel<<<(N * 128 + 255) / 256, 256, 0, stream>>>(h, hb, flag, N * 128);

    if (big) {
        hipMemsetAsync((void*)(ws + A), 0, (size_t)N * 8, stream);  // cnt + cur
        count_kernel<<<(E + 255) / 256, 256, 0, stream>>>(erow, cnt, E);
        scan_kernel<<<1, 1024, 0, stream>>>(cnt, offp, N);
        fill_kernel<<<(E + 255) / 256, 256, 0, stream>>>(erow, offp, cur, elist, E);

        edge_kernel<false><<<(E + 63) / 64, 256, 0, stream>>>(
            hb, x, eattr, erow, ecol, W1t, W2t, cW1t, iW1t,
            b1f, b2f, cb1f, cw2f, ib1f, iw2f, ib2f,
            mbuf, xbuf, nullptr, nullptr, E, flag);

        node_kernel<true><<<N, 128, 0, stream>>>(
            hb, x, v_init, mbuf, xbuf, offp, cnt, elist, nullptr, nullptr,
            nW1f, nb1f, nW2f, nb2f, vW1f, vb1f, vW2f,
            d_out, N * 128, N * 131, 1.0f / (float)(N - 1), flag);
    } else {
        hipMemsetAsync((void*)(ws + A), 0, (size_t)N * 528, stream);  // cnt+agg_x+m_i
        count_kernel<<<(E + 255) / 256, 256, 0, stream>>>(erow, cnt, E);

        edge_kernel<true><<<(E + 63) / 64, 256, 0, stream>>>(
            hb, x, eattr, erow, ecol, W1t, W2t, cW1t, iW1t,
            b1f, b2f, cb1f, cw2f, ib1f, iw2f, ib2f,
            nullptr, nullptr, m_i, agg_x, E, flag);

        node_kernel<false><<<N, 128, 0, stream>>>(
            hb, x, v_init, nullptr, nullptr, nullptr, cnt, nullptr, m_i, agg_x,
            nW1f, nb1f, nW2f, nb2f, vW1f, vb1f, vW2f,
            d_out, N * 128, N * 131, 1.0f / (float)(N - 1), flag);
    }
}

// Round 5
// 1738.056 us; speedup vs baseline: 1.2943x; 1.2943x over previous
//
#include <hip/hip_runtime.h>
#include <hip/hip_bf16.h>

typedef __attribute__((ext_vector_type(8))) short short8;
typedef __attribute__((ext_vector_type(4))) float f32x4;
typedef __hip_bfloat16 bf16;

__device__ __forceinline__ short f2bs(float f) {
    bf16 b = __float2bfloat16(f);
    return *reinterpret_cast<const short*>(&b);
}
__device__ __forceinline__ float bs2f(short s) {
    bf16 b = *reinterpret_cast<const bf16*>(&s);
    return __bfloat162float(b);
}
__device__ __forceinline__ float ldf(const void* p, int i, int flag) {
    return flag ? bs2f(((const short*)p)[i]) : ((const float*)p)[i];
}
__device__ __forceinline__ short ldbits(const void* p, int i, int flag) {
    return flag ? ((const short*)p)[i] : f2bs(((const float*)p)[i]);
}
__device__ __forceinline__ void stf(void* p, int i, float v, int flag) {
    if (flag) ((bf16*)p)[i] = __float2bfloat16(v);
    else ((float*)p)[i] = v;
}
__device__ __forceinline__ float nz(float v) { return (v == v) ? v : 0.f; }
// unclamped: silu(-inf)->-0, sigm(-inf)->0 — correct limits, no NaN for finite v
__device__ __forceinline__ float siluf(float v) { return v / (1.f + __expf(-v)); }
__device__ __forceinline__ float sigmf(float v) { return 1.f / (1.f + __expf(-v)); }

// ---------------------------------------------------------------------------
__global__ void detect_kernel(const unsigned int* __restrict__ hw, int* __restrict__ flag) {
    unsigned int w = hw[threadIdx.x];
    unsigned int e = (w >> 7) & 0xFF;
    bool ok = (e >= 113 && e <= 135);
    unsigned long long m = __ballot(ok);
    if (threadIdx.x == 0) *flag = (__popcll(m) >= 32) ? 1 : 0;
}

// ---------------------------------------------------------------------------
// prep: transposed bf16 edge weights, fp32 bias block, bf16 node/vel weights
// ---------------------------------------------------------------------------
__global__ void prep_kernel(
    const void* eW1, const void* eW2, const void* cW1, const void* iW1,
    const void* eb1, const void* eb2, const void* cb1, const void* cw2,
    const void* ib1, const void* iw2, const void* ib2, const void* nb1,
    const void* nb2, const void* vb1, const void* vW2,
    const void* nW1, const void* nW2, const void* vW1,
    short* __restrict__ W1t, short* __restrict__ W2t,
    short* __restrict__ cW1t, short* __restrict__ iW1t,
    float* __restrict__ biasblk, short* __restrict__ nW1b,
    short* __restrict__ nW2b, short* __restrict__ vW1b,
    const int* __restrict__ flagp) {
    const int flag = *flagp;
    int i = blockIdx.x * 256 + threadIdx.x;
    if (i < 36864) { int n = i / 288, k = i % 288; W1t[i] = (k < 258) ? ldbits(eW1, k * 128 + n, flag) : (short)0; return; }
    i -= 36864;
    if (i < 16384) { int n = i / 128, k = i % 128; W2t[i] = ldbits(eW2, k * 128 + n, flag); return; }
    i -= 16384;
    if (i < 16384) { int n = i / 128, k = i % 128; cW1t[i] = ldbits(cW1, k * 128 + n, flag); return; }
    i -= 16384;
    if (i < 8192) { int n = i / 128, k = i % 128; iW1t[i] = ldbits(iW1, k * 64 + n, flag); return; }
    i -= 8192;
    if (i < 1156) {
        float v;
        if (i < 128) v = ldf(eb1, i, flag);
        else if (i < 256) v = ldf(eb2, i - 128, flag);
        else if (i < 384) v = ldf(cb1, i - 256, flag);
        else if (i < 512) v = ldf(cw2, i - 384, flag);
        else if (i < 576) v = ldf(ib1, i - 512, flag);
        else if (i < 640) v = ldf(iw2, i - 576, flag);
        else if (i < 644) v = (i == 640) ? ldf(ib2, 0, flag) : 0.f;
        else if (i < 772) v = ldf(nb1, i - 644, flag);
        else if (i < 900) v = ldf(nb2, i - 772, flag);
        else if (i < 1028) v = ldf(vb1, i - 900, flag);
        else v = ldf(vW2, i - 1028, flag);
        biasblk[i] = v;
        return;
    }
    i -= 1156;
    if (i < 32768) { nW1b[i] = ldbits(nW1, i, flag); return; }
    i -= 32768;
    if (i < 16384) { nW2b[i] = ldbits(nW2, i, flag); return; }
    i -= 16384;
    if (i < 16384) { vW1b[i] = ldbits(vW1, i, flag); }
}

// ---------------------------------------------------------------------------
__global__ void convh_kernel(const void* __restrict__ h, short* __restrict__ hb,
                             const int* __restrict__ flagp, int n) {
    const int flag = *flagp;
    int i = blockIdx.x * 256 + threadIdx.x;
    if (i < n) hb[i] = ldbits(h, i, flag);
}

// x -> xf (fp32 N*3), eattr -> eaf (fp32 E)
__global__ void convaux_kernel(const void* __restrict__ x, const void* __restrict__ ea,
                               float* __restrict__ xf, float* __restrict__ eaf,
                               const int* __restrict__ flagp, int nx, int ne) {
    const int flag = *flagp;
    int i = blockIdx.x * 256 + threadIdx.x;
    if (i < nx) { xf[i] = ldf(x, i, flag); return; }
    i -= nx;
    if (i < ne) eaf[i] = ldf(ea, i, flag);
}

// ---------------------------------------------------------------------------
// CSR build: count -> hierarchical scan -> fill
// ---------------------------------------------------------------------------
__global__ void count_kernel(const int* __restrict__ erow, int* __restrict__ cnt, int E) {
    int i = blockIdx.x * 256 + threadIdx.x;
    if (i < E) atomicAdd(&cnt[erow[i]], 1);
}

__global__ __launch_bounds__(1024) void scan1_kernel(const int* __restrict__ cnt,
                                                     int* __restrict__ off,
                                                     int* __restrict__ bsum, int N) {
    __shared__ int sm[1024];
    int t = threadIdx.x, i = blockIdx.x * 1024 + t;
    int c = (i < N) ? cnt[i] : 0;
    sm[t] = c;
    __syncthreads();
    for (int d = 1; d < 1024; d <<= 1) {
        int v = (t >= d) ? sm[t - d] : 0;
        __syncthreads();
        sm[t] += v;
        __syncthreads();
    }
    if (i < N) off[i] = sm[t] - c;
    if (t == 1023) bsum[blockIdx.x] = sm[1023];
}
__global__ void scan2_kernel(const int* __restrict__ bsum, int* __restrict__ bpre, int nb) {
    if (threadIdx.x == 0) {
        int run = 0;
        for (int b = 0; b < nb; ++b) { bpre[b] = run; run += bsum[b]; }
    }
}
__global__ void scan3_kernel(int* __restrict__ off, const int* __restrict__ bpre, int N) {
    int i = blockIdx.x * 256 + threadIdx.x;
    if (i < N) off[i] += bpre[i >> 10];
}

__global__ void fill_kernel(const int* __restrict__ erow, const int* __restrict__ off,
                            int* __restrict__ cur, int* __restrict__ elist, int E) {
    int i = blockIdx.x * 256 + threadIdx.x;
    if (i < E) {
        int r = erow[i];
        int p = off[r] + atomicAdd(&cur[r], 1);
        elist[p] = i;
    }
}

// ---------------------------------------------------------------------------
// edge kernel: block = 256 thr = 4 waves; wave = 32 edges (2 m-tiles of 16).
// Weights staged in LDS (16 KB slices, row stride 72 shorts: 16B-aligned,
// 2-way-bank-free). Per-wave tiles for the C->A transpose (no block syncs).
// ---------------------------------------------------------------------------
__device__ __forceinline__ void stage_w(const short* __restrict__ src, int grs, int k0,
                                        int nrows, int wk, short* __restrict__ sW, int tid) {
    const int upr = wk >> 3;
    const int units = nrows * upr;
    for (int u = tid; u < units; u += 256) {
        int n = u / upr, c = u % upr;
        *(short8*)(sW + n * 72 + c * 8) = *(const short8*)(src + n * grs + k0 + c * 8);
    }
}

template <bool ATOMIC>
__global__ __launch_bounds__(256, 2) void edge_kernel(
    const short* __restrict__ hb, const float* __restrict__ xf,
    const float* __restrict__ eaf,
    const int* __restrict__ erow, const int* __restrict__ ecol,
    const short* __restrict__ W1t, const short* __restrict__ W2t,
    const short* __restrict__ cW1t, const short* __restrict__ iW1t,
    const float* __restrict__ biasblk,
    float* __restrict__ mbuf, float* __restrict__ xbuf,
    float* __restrict__ m_i, float* __restrict__ agg_x, int E) {
    __shared__ __align__(16) short sW[128 * 72];       // 18432 B
    __shared__ __align__(16) short tiles[8][16 * 136]; // 34816 B  (per wave*2+m)
    const float* b1f = biasblk;
    const float* b2f = biasblk + 128;
    const float* cb1f = biasblk + 256;
    const float* cw2f = biasblk + 384;
    const float* ib1f = biasblk + 512;
    const float* iw2f = biasblk + 576;
    const float ib2s = biasblk[640];

    const int tid = threadIdx.x;
    const int wv = tid >> 6;
    const int lane = tid & 63;
    const int n15 = lane & 15;
    const int quad = lane >> 4;
    const int wb = blockIdx.x * 128 + wv * 32;

    int row_e[2], col_e[2];
    float dist[2], attr[2];
#pragma unroll
    for (int m = 0; m < 2; ++m) {
        int e = wb + m * 16 + n15;
        int eL = (e < E) ? e : (E - 1);
        row_e[m] = erow[eL];
        col_e[m] = ecol[eL];
        float d = 0.f;
#pragma unroll
        for (int dd = 0; dd < 3; ++dd) {
            float xd = xf[row_e[m] * 3 + dd] - xf[col_e[m] * 3 + dd];
            d += xd * xd;
        }
        dist[m] = d;
        attr[m] = eaf[eL];
    }

    // ---- GEMM1: ef[32 x 288] @ W1 (K padded to 288, 5 slices of <=64k)
    f32x4 acc1[2][8];
#pragma unroll
    for (int m = 0; m < 2; ++m)
#pragma unroll
        for (int nt = 0; nt < 8; ++nt) acc1[m][nt] = (f32x4){0.f, 0.f, 0.f, 0.f};

    for (int s = 0; s < 5; ++s) {
        const int k0 = s * 64;
        const int wk = (s < 4) ? 64 : 32;
        __syncthreads();
        stage_w(W1t, 288, k0, 128, wk, sW, tid);
        __syncthreads();
        const int kcs = (s < 4) ? 2 : 1;
        for (int kc2 = 0; kc2 < kcs; ++kc2) {
            const int kglob = k0 + kc2 * 32;
            short8 a[2];
#pragma unroll
            for (int m = 0; m < 2; ++m) {
                if (kglob < 128) {
                    a[m] = *(const short8*)(hb + row_e[m] * 128 + kglob + quad * 8);
                } else if (kglob < 256) {
                    a[m] = *(const short8*)(hb + col_e[m] * 128 + (kglob - 128) + quad * 8);
                } else {
#pragma unroll
                    for (int t = 0; t < 8; ++t) a[m][t] = 0;
                    if (quad == 0) { a[m][0] = f2bs(dist[m]); a[m][1] = f2bs(attr[m]); }
                }
            }
#pragma unroll
            for (int nt = 0; nt < 8; ++nt) {
                short8 b = *(const short8*)(sW + (nt * 16 + n15) * 72 + kc2 * 32 + quad * 8);
                acc1[0][nt] = __builtin_amdgcn_mfma_f32_16x16x32_bf16(a[0], b, acc1[0][nt], 0, 0, 0);
                acc1[1][nt] = __builtin_amdgcn_mfma_f32_16x16x32_bf16(a[1], b, acc1[1][nt], 0, 0, 0);
            }
        }
    }

    // hidden1 -> per-wave tiles (wave-private: no block barrier needed)
#pragma unroll
    for (int m = 0; m < 2; ++m) {
        short* tl = tiles[wv * 2 + m];
#pragma unroll
        for (int nt = 0; nt < 8; ++nt) {
            float bv = b1f[nt * 16 + n15];
#pragma unroll
            for (int r = 0; r < 4; ++r)
                tl[(quad * 4 + r) * 136 + nt * 16 + n15] = f2bs(siluf(acc1[m][nt][r] + bv));
        }
    }

    // ---- GEMM2: hidden1 @ W2 (2 slices)
    f32x4 acc2[2][8];
#pragma unroll
    for (int m = 0; m < 2; ++m)
#pragma unroll
        for (int nt = 0; nt < 8; ++nt) acc2[m][nt] = (f32x4){0.f, 0.f, 0.f, 0.f};
    for (int s = 0; s < 2; ++s) {
        __syncthreads();
        stage_w(W2t, 128, s * 64, 128, 64, sW, tid);
        __syncthreads();
        for (int kc2 = 0; kc2 < 2; ++kc2) {
            const int kc = s * 2 + kc2;
            short8 a[2];
#pragma unroll
            for (int m = 0; m < 2; ++m)
                a[m] = *(const short8*)(tiles[wv * 2 + m] + n15 * 136 + kc * 32 + quad * 8);
#pragma unroll
            for (int nt = 0; nt < 8; ++nt) {
                short8 b = *(const short8*)(sW + (nt * 16 + n15) * 72 + kc2 * 32 + quad * 8);
                acc2[0][nt] = __builtin_amdgcn_mfma_f32_16x16x32_bf16(a[0], b, acc2[0][nt], 0, 0, 0);
                acc2[1][nt] = __builtin_amdgcn_mfma_f32_16x16x32_bf16(a[1], b, acc2[1][nt], 0, 0, 0);
            }
        }
    }

    // m_ij -> mv regs + rewrite tiles
    float mv[2][8][4];
#pragma unroll
    for (int m = 0; m < 2; ++m) {
        short* tl = tiles[wv * 2 + m];
#pragma unroll
        for (int nt = 0; nt < 8; ++nt) {
            float bv = b2f[nt * 16 + n15];
#pragma unroll
            for (int r = 0; r < 4; ++r) {
                float v = siluf(acc2[m][nt][r] + bv);
                mv[m][nt][r] = v;
                tl[(quad * 4 + r) * 136 + nt * 16 + n15] = f2bs(v);
            }
        }
    }

    // ---- GEMM4 first (inf, 64 cols) -> eij, then free acc4
    f32x4 acc4[2][4];
#pragma unroll
    for (int m = 0; m < 2; ++m)
#pragma unroll
        for (int nt = 0; nt < 4; ++nt) acc4[m][nt] = (f32x4){0.f, 0.f, 0.f, 0.f};
    for (int s = 0; s < 2; ++s) {
        __syncthreads();
        stage_w(iW1t, 128, s * 64, 64, 64, sW, tid);
        __syncthreads();
        for (int kc2 = 0; kc2 < 2; ++kc2) {
            const int kc = s * 2 + kc2;
            short8 a[2];
#pragma unroll
            for (int m = 0; m < 2; ++m)
                a[m] = *(const short8*)(tiles[wv * 2 + m] + n15 * 136 + kc * 32 + quad * 8);
#pragma unroll
            for (int nt = 0; nt < 4; ++nt) {
                short8 b = *(const short8*)(sW + (nt * 16 + n15) * 72 + kc2 * 32 + quad * 8);
                acc4[0][nt] = __builtin_amdgcn_mfma_f32_16x16x32_bf16(a[0], b, acc4[0][nt], 0, 0, 0);
                acc4[1][nt] = __builtin_amdgcn_mfma_f32_16x16x32_bf16(a[1], b, acc4[1][nt], 0, 0, 0);
            }
        }
    }
    float eij[2][4];
#pragma unroll
    for (int m = 0; m < 2; ++m) {
        float inp[4] = {0.f, 0.f, 0.f, 0.f};
#pragma unroll
        for (int nt = 0; nt < 4; ++nt) {
            float ib = ib1f[nt * 16 + n15];
            float iw = iw2f[nt * 16 + n15];
#pragma unroll
            for (int r = 0; r < 4; ++r) inp[r] += siluf(acc4[m][nt][r] + ib) * iw;
        }
#pragma unroll
        for (int mk = 1; mk < 16; mk <<= 1)
#pragma unroll
            for (int r = 0; r < 4; ++r) inp[r] += __shfl_xor(inp[r], mk);
#pragma unroll
        for (int r = 0; r < 4; ++r) eij[m][r] = sigmf(inp[r] + ib2s);
    }

    // ---- GEMM3 (coord) -> phi
    f32x4 acc3[2][8];
#pragma unroll
    for (int m = 0; m < 2; ++m)
#pragma unroll
        for (int nt = 0; nt < 8; ++nt) acc3[m][nt] = (f32x4){0.f, 0.f, 0.f, 0.f};
    for (int s = 0; s < 2; ++s) {
        __syncthreads();
        stage_w(cW1t, 128, s * 64, 128, 64, sW, tid);
        __syncthreads();
        for (int kc2 = 0; kc2 < 2; ++kc2) {
            const int kc = s * 2 + kc2;
            short8 a[2];
#pragma unroll
            for (int m = 0; m < 2; ++m)
                a[m] = *(const short8*)(tiles[wv * 2 + m] + n15 * 136 + kc * 32 + quad * 8);
#pragma unroll
            for (int nt = 0; nt < 8; ++nt) {
                short8 b = *(const short8*)(sW + (nt * 16 + n15) * 72 + kc2 * 32 + quad * 8);
                acc3[0][nt] = __builtin_amdgcn_mfma_f32_16x16x32_bf16(a[0], b, acc3[0][nt], 0, 0, 0);
                acc3[1][nt] = __builtin_amdgcn_mfma_f32_16x16x32_bf16(a[1], b, acc3[1][nt], 0, 0, 0);
            }
        }
    }

    // ---- stores per m-tile
#pragma unroll
    for (int m = 0; m < 2; ++m) {
        float php[4] = {0.f, 0.f, 0.f, 0.f};
#pragma unroll
        for (int nt = 0; nt < 8; ++nt) {
            float cb = cb1f[nt * 16 + n15];
            float cw = cw2f[nt * 16 + n15];
#pragma unroll
            for (int r = 0; r < 4; ++r) php[r] += siluf(acc3[m][nt][r] + cb) * cw;
        }
#pragma unroll
        for (int mk = 1; mk < 16; mk <<= 1)
#pragma unroll
            for (int r = 0; r < 4; ++r) php[r] += __shfl_xor(php[r], mk);

        int er[4], ec[4];
        bool mk4[4];
#pragma unroll
        for (int r = 0; r < 4; ++r) {
            er[r] = __shfl(row_e[m], quad * 4 + r);
            ec[r] = __shfl(col_e[m], quad * 4 + r);
            mk4[r] = (wb + m * 16 + quad * 4 + r) < E;
        }
        if (ATOMIC) {
#pragma unroll
            for (int nt = 0; nt < 8; ++nt)
#pragma unroll
                for (int r = 0; r < 4; ++r)
                    if (mk4[r]) atomicAdd(&m_i[er[r] * 128 + nt * 16 + n15],
                                          nz(eij[m][r] * mv[m][nt][r]));
            if (n15 == 0) {
#pragma unroll
                for (int r = 0; r < 4; ++r) {
                    if (!mk4[r]) continue;
                    float s = eij[m][r] * php[r];
#pragma unroll
                    for (int d = 0; d < 3; ++d) {
                        float xd = xf[er[r] * 3 + d] - xf[ec[r] * 3 + d];
                        atomicAdd(&agg_x[er[r] * 3 + d], nz(s * xd));
                    }
                }
            }
        } else {
#pragma unroll
            for (int nt = 0; nt < 8; ++nt)
#pragma unroll
                for (int r = 0; r < 4; ++r)
                    if (mk4[r])
                        mbuf[(size_t)(wb + m * 16 + quad * 4 + r) * 128 + nt * 16 + n15] =
                            nz(eij[m][r] * mv[m][nt][r]);
            if (n15 < 3) {
#pragma unroll
                for (int r = 0; r < 4; ++r) {
                    if (!mk4[r]) continue;
                    float s = eij[m][r] * php[r];
                    float xd = xf[er[r] * 3 + n15] - xf[ec[r] * 3 + n15];
                    xbuf[(size_t)(wb + m * 16 + quad * 4 + r) * 4 + n15] = nz(s * xd);
                }
            }
        }
    }
}

// ---------------------------------------------------------------------------
// node kernel: 512 thr = 4 node-lanes x 128, 8 nodes/block (2 iterations).
// gather m_i via CSR, vel MLP + node MLP (bf16 weights), x_out, v_out.
// ---------------------------------------------------------------------------
template <bool GATHER>
__global__ __launch_bounds__(512) void node_kernel(
    const short* __restrict__ hb, const float* __restrict__ xf,
    const void* __restrict__ v_init,
    const float* __restrict__ mbuf, const float* __restrict__ xbuf,
    const int* __restrict__ off, const int* __restrict__ cnt,
    const int* __restrict__ elist,
    const float* __restrict__ m_i, const float* __restrict__ agg_x,
    const short* __restrict__ nW1b, const short* __restrict__ nW2b,
    const short* __restrict__ vW1b, const float* __restrict__ biasblk,
    void* __restrict__ out, int N, int xbase, int vbase, float inv_nm1,
    const int* __restrict__ flagp) {
    const int flag = *flagp;
    const float* nb1f = biasblk + 644;
    const float* nb2f = biasblk + 772;
    const float* vb1f = biasblk + 900;
    const float* vW2f = biasblk + 1028;
    __shared__ float nin[4][256];
    __shared__ float red[4][128];
    __shared__ float hid[4][128];
    const int slot = threadIdx.x >> 7;
    const int j = threadIdx.x & 127;

    for (int it = 0; it < 2; ++it) {
        const int n = blockIdx.x * 8 + it * 4 + slot;
        const bool act = (n < N);
        const int na = act ? n : (N - 1);

        nin[slot][j] = bs2f(hb[na * 128 + j]);
        const int c = cnt[na];
        float msum = 0.f;
        if (GATHER) {
            const int s0 = off[na];
            for (int i = 0; i < c; ++i) {
                int eid = elist[s0 + i];
                msum += mbuf[(size_t)eid * 128 + j];
            }
        } else {
            msum = m_i[na * 128 + j];
        }
        nin[slot][128 + j] = nz(msum);
        __syncthreads();

        // vel MLP
        float vacc = vb1f[j];
#pragma unroll 8
        for (int k = 0; k < 128; ++k) vacc += nin[slot][k] * bs2f(vW1b[k * 128 + j]);
        red[slot][j] = siluf(vacc) * vW2f[j];
        __syncthreads();
        for (int s = 64; s > 0; s >>= 1) {
            if (j < s) red[slot][j] += red[slot][j + s];
            __syncthreads();
        }
        const float vscale = red[slot][0];

        // node MLP
        float acc = nb1f[j];
#pragma unroll 8
        for (int k = 0; k < 256; ++k) acc += nin[slot][k] * bs2f(nW1b[k * 128 + j]);
        hid[slot][j] = siluf(acc);
        __syncthreads();
        float o = nb2f[j];
#pragma unroll 8
        for (int k = 0; k < 128; ++k) o += hid[slot][k] * bs2f(nW2b[k * 128 + j]);
        if (act) stf(out, n * 128 + j, nz(o), flag);

        if (act && j < 3) {
            float vj = nz(ldf(v_init, n * 3 + j, flag) * vscale);
            stf(out, vbase + n * 3 + j, vj, flag);
            float xv = xf[n * 3 + j];
            float ax;
            if (GATHER) {
                ax = 0.f;
                const int s0 = off[na];
                for (int i = 0; i < c; ++i) {
                    int eid = elist[s0 + i];
                    ax += xbuf[(size_t)eid * 4 + j];
                }
            } else {
                ax = agg_x[n * 3 + j];
            }
            float xo = (c > 0) ? xv + vj + nz(ax) * inv_nm1 : xv;
            stf(out, xbase + n * 3 + j, nz(xo), flag);
        }
        __syncthreads();
    }
}

// ---------------------------------------------------------------------------
extern "C" void kernel_launch(void* const* d_in, const int* in_sizes, int n_in,
                              void* d_out, int out_size, void* d_ws, size_t ws_size,
                              hipStream_t stream) {
    const void* h = d_in[0];
    const void* x = d_in[1];
    const void* eattr = d_in[2];
    const void* v_init = d_in[3];
    const int* eidx = (const int*)d_in[4];

    const int N = in_sizes[0] / 128;
    const int E = in_sizes[4] / 2;
    const int* erow = eidx;
    const int* ecol = eidx + E;

    char* ws = (char*)d_ws;
    int* flag = (int*)ws;                       // 256
    short* W1t = (short*)(ws + 256);            // 73728
    short* W2t = (short*)(ws + 73984);          // 32768
    short* cW1t = (short*)(ws + 106752);        // 32768
    short* iW1t = (short*)(ws + 139520);        // 16384
    float* biasblk = (float*)(ws + 155904);     // 4624 -> pad 160768
    short* nW1b = (short*)(ws + 160768);        // 65536
    short* nW2b = (short*)(ws + 226304);        // 32768
    short* vW1b = (short*)(ws + 259072);        // 32768
    int* bsum = (int*)(ws + 291840);            // 512
    int* bpre = (int*)(ws + 292352);            // 512
    short* hb = (short*)(ws + 292864);          // N*256
    size_t o = 292864 + (size_t)N * 256;
    float* xf = (float*)(ws + o); o += (size_t)N * 12;
    float* eaf = (float*)(ws + o); o += (size_t)E * 4;
    size_t oCnt = o;
    int* cnt = (int*)(ws + o); o += (size_t)N * 4;
    // big path
    size_t oCur = o;
    int* cur = (int*)(ws + o); o += (size_t)N * 4;
    int* offp = (int*)(ws + o); o += (size_t)(N + 16) * 4;
    int* elist = (int*)(ws + o); o += (size_t)E * 4;
    float* xbuf = (float*)(ws + o); o += (size_t)E * 16;
    float* mbuf = (float*)(ws + o); o += (size_t)E * 512;
    const size_t need_big = o;
    // fallback overlay (after cnt)
    float* fb_agg = (float*)(ws + oCur);
    float* fb_mi = (float*)(ws + oCur + (size_t)N * 16);

    const bool big = (ws_size >= need_big);

    detect_kernel<<<1, 64, 0, stream>>>((const unsigned int*)h, flag);

    const int prep_elems = 36864 + 16384 + 16384 + 8192 + 1156 + 32768 + 16384 + 16384;
    prep_kernel<<<(prep_elems + 255) / 256, 256, 0, stream>>>(
        d_in[5], d_in[7], d_in[9], d_in[12],
        d_in[6], d_in[8], d_in[10], d_in[11], d_in[13], d_in[14], d_in[15],
        d_in[17], d_in[19], d_in[21], d_in[22],
        d_in[16], d_in[18], d_in[20],
        W1t, W2t, cW1t, iW1t, biasblk, nW1b, nW2b, vW1b, flag);

    convh_kernel<<<(N * 128 + 255) / 256, 256, 0, stream>>>(h, hb, flag, N * 128);
    convaux_kernel<<<(N * 3 + E + 255) / 256, 256, 0, stream>>>(x, eattr, xf, eaf, flag,
                                                               N * 3, E);

    if (big) {
        hipMemsetAsync((void*)(ws + oCnt), 0, (size_t)N * 8, stream);  // cnt+cur
        count_kernel<<<(E + 255) / 256, 256, 0, stream>>>(erow, cnt, E);
        const int nb = (N + 1023) / 1024;
        scan1_kernel<<<nb, 1024, 0, stream>>>(cnt, offp, bsum, N);
        scan2_kernel<<<1, 64, 0, stream>>>(bsum, bpre, nb);
        scan3_kernel<<<(N + 255) / 256, 256, 0, stream>>>(offp, bpre, N);
        fill_kernel<<<(E + 255) / 256, 256, 0, stream>>>(erow, offp, cur, elist, E);

        edge_kernel<false><<<(E + 127) / 128, 256, 0, stream>>>(
            hb, xf, eaf, erow, ecol, W1t, W2t, cW1t, iW1t, biasblk,
            mbuf, xbuf, nullptr, nullptr, E);

        node_kernel<true><<<(N + 7) / 8, 512, 0, stream>>>(
            hb, xf, v_init, mbuf, xbuf, offp, cnt, elist, nullptr, nullptr,
            nW1b, nW2b, vW1b, biasblk, d_out, N, N * 128, N * 131,
            1.0f / (float)(N - 1), flag);
    } else {
        hipMemsetAsync((void*)(ws + oCnt), 0, (size_t)N * 4 + (size_t)N * 16 + (size_t)N * 512,
                       stream);
        count_kernel<<<(E + 255) / 256, 256, 0, stream>>>(erow, cnt, E);

        edge_kernel<true><<<(E + 127) / 128, 256, 0, stream>>>(
            hb, xf, eaf, erow, ecol, W1t, W2t, cW1t, iW1t, biasblk,
            nullptr, nullptr, fb_mi, fb_agg, E);

        node_kernel<false><<<(N + 7) / 8, 512, 0, stream>>>(
            hb, xf, v_init, nullptr, nullptr, nullptr, cnt, nullptr, fb_mi, fb_agg,
            nW1b, nW2b, vW1b, biasblk, d_out, N, N * 128, N * 131,
            1.0f / (float)(N - 1), flag);
    }
}